// Round 21
// baseline (187.151 us; speedup 1.0000x reference)
//
#include <hip/hip_runtime.h>
#include <cmath>

#define DIM 16
#define VOCAB 18
#define TLEN 2048
#define NBLK (TLEN / 64)
#define TWO_LOG2E 2.8853900817779268f  // 2*log2(e)

// Load float input element idx, from either a bf16 or f32 device buffer.
__device__ __forceinline__ float ldf(const void* p, int idx, int isbf) {
    if (isbf) {
        unsigned int w = ((const unsigned short*)p)[idx];
        return __uint_as_float(w << 16);
    }
    return ((const float*)p)[idx];
}

// ---------------------------------------------------------------------------
// Detector 1: token width. int64 tokens (0..17) have all odd 32-bit words 0.
// ---------------------------------------------------------------------------
__global__ void detect_tok(const int* __restrict__ x32, int* __restrict__ flag) {
    int v = 0;
    for (int j = threadIdx.x; j < 4096; j += 64) v |= x32[2 * j + 1];
    unsigned long long any = __ballot(v != 0);
    if (threadIdx.x == 0) flag[0] = (any == 0ULL) ? 1 : 0;
}

// ---------------------------------------------------------------------------
// Detector 2: float width. bf16 words of N(0,1) data have exponent in
// [90,140]; f32 lo-mantissa words are uniform random -> certain failure.
// ---------------------------------------------------------------------------
__global__ void detect_f(const unsigned short* __restrict__ emb16,
                         int* __restrict__ flag) {
    int bad = 0;
    for (int j = threadIdx.x; j < VOCAB * DIM; j += 64) {
        unsigned short w = emb16[j];
        int e = (w >> 7) & 0xFF;
        if (!((e >= 90 && e <= 140) || (w & 0x7FFF) == 0)) bad = 1;
    }
    unsigned long long anybad = __ballot(bad);
    if (threadIdx.x == 0) flag[1] = (anybad == 0ULL) ? 1 : 0;
}

// ---------------------------------------------------------------------------
// Setup: wtab[v][k] = sum_d emb[v,d] * W_w[k,d] + W_b[k]   (18 x 16, f32)
// ---------------------------------------------------------------------------
__global__ void wtab_kernel(const void* __restrict__ emb,
                            const void* __restrict__ W_w,
                            const void* __restrict__ W_b,
                            const int* __restrict__ flag,
                            float* __restrict__ wtab) {
    int tid = threadIdx.x;
    int isbf = flag[1];
    if (tid < VOCAB * DIM) {
        int v = tid >> 4, kk = tid & 15;
        float s = ldf(W_b, kk, isbf);
#pragma unroll
        for (int d = 0; d < DIM; ++d)
            s = fmaf(ldf(emb, v * DIM + d, isbf), ldf(W_w, kk * DIM + d, isbf), s);
        wtab[tid] = s;
    }
}

// DPP row-rotate (builtin: compiler inserts hazard nops, incl. after TRANS).
template <int CTRL>
__device__ __forceinline__ float ror_f(float v) {
    return __int_as_float(
        __builtin_amdgcn_mov_dpp(__float_as_int(v), CTRL, 0xF, 0xF, true));
}

// Sum across the lane<->lane+32 pair (both lanes get the full sum).
__device__ __forceinline__ float pair_sum32(float p) {
#if __has_builtin(__builtin_amdgcn_permlane32_swap)
    typedef int i32x2 __attribute__((ext_vector_type(2)));
    i32x2 sw = __builtin_amdgcn_permlane32_swap(__float_as_int(p),
                                                __float_as_int(p), false, false);
    return __int_as_float(sw.x) + __int_as_float(sw.y);
#else
    return p + __shfl_xor(p, 32, 64);
#endif
}

#define WSTR 19    // wtabT row stride: gcd(19,32)=1 -> 16 lanes, 16 banks
#define WHIB 304   // hi-half zero-region base (16*19)
#define WZLEN 608  // rows 0..303 real, 304..607 zeros
#define SSTR 68    // slab element stride in words (16B-aligned)

// ---------------------------------------------------------------------------
// Main RNN kernel: 32 lanes/element (R18-validated layout) + R20's lean core.
// State r = 1/(2^S+1)  (h = 1-2r folded into weights/const table):
//   S = scale*(wtab[tok][k]+rowsumU[k]) + sum_j (-2*scale*U[k][dj]) * r[dj]
// lane (row,k): rows 0,1 = elems A,B terms 0-7; rows 2,3 = terms 8-15
// (base = ror8(r), hazard-safe builtin). 8 MACs: 1 fmaf + 7 fused VOP2+DPP
// in ONE asm block (s_nop 0 + fmaf shield after cndmask — R18-proven safe).
// Halves summed via permlane32_swap. Tokens: wave-private dbuf LDS slab;
// w-value 3 ahead, token 6 ahead. 512 thr/block, 256 blocks -> 2 waves/SIMD.
// ---------------------------------------------------------------------------
__global__ __launch_bounds__(512) void rnn_kernel(const int* __restrict__ x32,
                                                  const int* __restrict__ flag,
                                                  const float* __restrict__ wtab_g,
                                                  const void* __restrict__ U_w,
                                                  const void* __restrict__ head_w,
                                                  const void* __restrict__ head_b,
                                                  float* __restrict__ out) {
    __shared__ float wtabT[WZLEN];      // [k][v] stride 19, folded+prescaled
    __shared__ float sU[DIM * DIM];
    __shared__ float lds_h[16][DIM];
    __shared__ int slab[2][16 * SSTR];  // token slabs, wave-private slices

    const int tid = threadIdx.x;
    const int is64 = __builtin_amdgcn_readfirstlane(flag[0]);
    const int isbf = __builtin_amdgcn_readfirstlane(flag[1]);

    // Strided fills (never the guarded-single-store bug again).
    for (int i = tid; i < WZLEN; i += 512) {
        int r = i / WSTR, v = i - r * WSTR;
        float val = 0.0f;
        if (r < 16 && v < VOCAB) {
            float rs = 0.0f;
#pragma unroll
            for (int d = 0; d < DIM; ++d) rs += ldf(U_w, r * DIM + d, isbf);
            val = (wtab_g[v * DIM + r] + rs) * TWO_LOG2E;  // transposed+folded
        }
        wtabT[i] = val;
    }
    for (int i = tid; i < DIM * DIM; i += 512) sU[i] = ldf(U_w, i, isbf);
    __syncthreads();  // the only block-wide barrier until the head

    const int lane = tid & 63;
    const int wave = tid >> 6;
    const int row = lane >> 4;              // 0..3
    const int k = lane & 15;                // output dim owned by this lane
    const int half = row >> 1;              // 0: terms 0-7; 1: terms 8-15
    const int e = (wave << 1) | (row & 1);  // element within block
    const bool lo32 = (lane < 32);
    const int gelem = (blockIdx.x << 4) | e;

    // Probe DPP ror direction (validated R12-R20).
    int p = __builtin_amdgcn_mov_dpp(k, 0x121, 0xF, 0xF, true);
    int c = (p - k) & 15;

    // ur2[j] = -2 * scale * U[k][(k + (j + 8*half)*c) & 15].
    float ur2[8];
#pragma unroll
    for (int j = 0; j < 8; ++j)
        ur2[j] = sU[(k << 4) | ((k + (j + 8 * half) * c) & 15)] *
                 (-2.0f * TWO_LOG2E);

    // wtab row base (float idx): lo half -> real row k; hi half -> zeros.
    const int wb = k * WSTR + half * WHIB;

    // Lane's token slots in global: steps 4k..4k+3 of each 64-step blk.
    const size_t tokbase = (size_t)gelem * TLEN + (k << 2);

    int* cur = &slab[0][e * SSTR];
    int* nxt = &slab[1][e * SSTR];

    int4 g0;
#define LOADG(G, B)                                                           \
    if (lo32) {                                                               \
        if (is64) {                                                           \
            const int* pp = x32 + ((tokbase + ((size_t)(B) << 6)) << 1);      \
            int4 a = *(const int4*)pp;                                        \
            int4 bq = *(const int4*)(pp + 4);                                 \
            G = make_int4(a.x, a.z, bq.x, bq.z);                              \
        } else {                                                              \
            G = *(const int4*)(x32 + tokbase + ((size_t)(B) << 6));           \
        }                                                                     \
    }

    // Prologue: slab0 <- blk0; gcur <- blk1; prime the pipelines.
    LOADG(g0, 0)
    if (lo32) *(int4*)(cur + (k << 2)) = g0;
    int4 gcur;
    LOADG(gcur, 1)

    int t3 = cur[3], t4 = cur[4], t5 = cur[5];
    float w0 = wtabT[wb + cur[0]];
    float w1 = wtabT[wb + cur[1]];
    float w2 = wtabT[wb + cur[2]];

    float rst = 0.5f;  // r-state for h0 = 0

    for (int b = 0; b < NBLK; ++b) {
        // Write next slab from gcur (loaded one blk ago), refill gcur.
        if (lo32) *(int4*)(nxt + (k << 2)) = gcur;
        const int nb2 = (b + 2 < NBLK) ? b + 2 : NBLK - 1;
        LOADG(gcur, nb2)

#pragma unroll
        for (int s = 0; s < 64; ++s) {
            // Base select first (builtin DPP: compiler shields TRANS write).
            float r8 = ror_f<0x128>(rst);
            // Token 6 ahead (imm-offset broadcast), w-value 3 ahead.
            int t6 = (s + 6 < 64) ? cur[s + 6] : nxt[s - 58];
            float w3 = wtabT[wb + t3];

            float bb = lo32 ? rst : r8;  // terms 0-7 use r; 8-15 use ror8(r)
            float a0 = fmaf(ur2[0], bb, w0);  // w0 = 0 for hi half (zero rows)
            float a1;
            // Monolithic: s_nop 0 + fmaf = >=3 cyc shield after cndmask(bb);
            // fixed order keeps DPPs clear of any TRANS write (R19 lesson).
            asm("s_nop 0\n\t"
                "v_mul_f32_dpp %[a1], %[b], %[u1] row_ror:1 row_mask:0xf bank_mask:0xf\n\t"
                "v_fmac_f32_dpp %[a0], %[b], %[u2] row_ror:2 row_mask:0xf bank_mask:0xf\n\t"
                "v_fmac_f32_dpp %[a1], %[b], %[u3] row_ror:3 row_mask:0xf bank_mask:0xf\n\t"
                "v_fmac_f32_dpp %[a0], %[b], %[u4] row_ror:4 row_mask:0xf bank_mask:0xf\n\t"
                "v_fmac_f32_dpp %[a1], %[b], %[u5] row_ror:5 row_mask:0xf bank_mask:0xf\n\t"
                "v_fmac_f32_dpp %[a0], %[b], %[u6] row_ror:6 row_mask:0xf bank_mask:0xf\n\t"
                "v_fmac_f32_dpp %[a1], %[b], %[u7] row_ror:7 row_mask:0xf bank_mask:0xf"
                : [a0] "+v"(a0), [a1] "=&v"(a1)
                : [b] "v"(bb), [u1] "v"(ur2[1]), [u2] "v"(ur2[2]),
                  [u3] "v"(ur2[3]), [u4] "v"(ur2[4]), [u5] "v"(ur2[5]),
                  [u6] "v"(ur2[6]), [u7] "v"(ur2[7]));

            float S = pair_sum32(a0 + a1);
            rst = __builtin_amdgcn_rcpf(__builtin_amdgcn_exp2f(S) + 1.0f);

            w0 = w1;
            w1 = w2;
            w2 = w3;
            t3 = t4;
            t4 = t5;
            t5 = t6;
        }
        int* tmp = cur;
        cur = nxt;
        nxt = tmp;
    }

    // Head: h = 1 - 2r; out[b,v] = h . head_w[v,:] + head_b[v], f32 store.
    if (lo32) lds_h[e][k] = fmaf(-2.0f, rst, 1.0f);
    __syncthreads();

    for (int i = tid; i < 16 * VOCAB; i += 512) {
        int ee = i / VOCAB;
        int v = i - ee * VOCAB;
        float s = ldf(head_b, v, isbf);
#pragma unroll
        for (int d = 0; d < DIM; ++d)
            s = fmaf(lds_h[ee][d], ldf(head_w, (v << 4) + d, isbf), s);
        out[(size_t)((blockIdx.x << 4) | ee) * VOCAB + v] = s;
    }
}

extern "C" void kernel_launch(void* const* d_in, const int* in_sizes, int n_in,
                              void* d_out, int out_size, void* d_ws, size_t ws_size,
                              hipStream_t stream) {
    const int* x = (const int*)d_in[0];
    const void* emb = d_in[1];
    const void* W_w = d_in[2];
    const void* W_b = d_in[3];
    const void* U_w = d_in[4];
    const void* head_w = d_in[5];
    const void* head_b = d_in[6];

    float* wtab = (float*)d_ws;              // 288 floats
    int* flag = (int*)((char*)d_ws + 4096);  // [0]=tok is64, [1]=floats are bf16

    detect_tok<<<1, 64, 0, stream>>>(x, flag);
    detect_f<<<1, 64, 0, stream>>>((const unsigned short*)emb, flag);
    wtab_kernel<<<1, 320, 0, stream>>>(emb, W_w, W_b, flag, wtab);
    rnn_kernel<<<256, 512, 0, stream>>>(x, flag, wtab, U_w, head_w, head_b,
                                        (float*)d_out);
}

// Round 22
// 149.083 us; speedup vs baseline: 1.2553x; 1.2553x over previous
//
#include <hip/hip_runtime.h>
#include <cmath>

#define DIM 16
#define VOCAB 18
#define TLEN 2048
#define NBLK (TLEN / 64)
#define TWO_LOG2E 2.8853900817779268f  // 2*log2(e)

// Load float input element idx, from either a bf16 or f32 device buffer.
__device__ __forceinline__ float ldf(const void* p, int idx, int isbf) {
    if (isbf) {
        unsigned int w = ((const unsigned short*)p)[idx];
        return __uint_as_float(w << 16);
    }
    return ((const float*)p)[idx];
}

// ---------------------------------------------------------------------------
// Detector 1: token width. int64 tokens (0..17) have all odd 32-bit words 0.
// ---------------------------------------------------------------------------
__global__ void detect_tok(const int* __restrict__ x32, int* __restrict__ flag) {
    int v = 0;
    for (int j = threadIdx.x; j < 4096; j += 64) v |= x32[2 * j + 1];
    unsigned long long any = __ballot(v != 0);
    if (threadIdx.x == 0) flag[0] = (any == 0ULL) ? 1 : 0;
}

// ---------------------------------------------------------------------------
// Detector 2: float width. bf16 words of N(0,1) data have exponent in
// [90,140]; f32 lo-mantissa words are uniform random -> certain failure.
// ---------------------------------------------------------------------------
__global__ void detect_f(const unsigned short* __restrict__ emb16,
                         int* __restrict__ flag) {
    int bad = 0;
    for (int j = threadIdx.x; j < VOCAB * DIM; j += 64) {
        unsigned short w = emb16[j];
        int e = (w >> 7) & 0xFF;
        if (!((e >= 90 && e <= 140) || (w & 0x7FFF) == 0)) bad = 1;
    }
    unsigned long long anybad = __ballot(bad);
    if (threadIdx.x == 0) flag[1] = (anybad == 0ULL) ? 1 : 0;
}

// ---------------------------------------------------------------------------
// Setup: wtab[v][k] = sum_d emb[v,d] * W_w[k,d] + W_b[k]   (18 x 16, f32)
// ---------------------------------------------------------------------------
__global__ void wtab_kernel(const void* __restrict__ emb,
                            const void* __restrict__ W_w,
                            const void* __restrict__ W_b,
                            const int* __restrict__ flag,
                            float* __restrict__ wtab) {
    int tid = threadIdx.x;
    int isbf = flag[1];
    if (tid < VOCAB * DIM) {
        int v = tid >> 4, kk = tid & 15;
        float s = ldf(W_b, kk, isbf);
#pragma unroll
        for (int d = 0; d < DIM; ++d)
            s = fmaf(ldf(emb, v * DIM + d, isbf), ldf(W_w, kk * DIM + d, isbf), s);
        wtab[tid] = s;
    }
}

#define WSTR 19   // wtabT row stride: spreads 16 lanes over 16 banks
#define SSTR 68   // slab element stride (16B aligned; groups 4 banks apart)

// ---------------------------------------------------------------------------
// Main RNN kernel (R20-validated form + grouped DS pipeline).
// 16 lanes per element, 4 elements/wave, full dot in-lane:
//   S_k = scale*(wtab[tok][k]+rowsumU[k]) + sum_j (-2*scale*U[k][dj])*r[dj]
//   r' = 1/(2^S+1)   (h = 1-2r folded into weights)
// MACs: 1 fmaf + ONE asm block (s_nop 1 + 15 fused VOP2+DPP row_ror, fixed
// order -> shielded from the TRANS v_rcp write; R19/R20-established).
// DS pipeline by 4-step groups: one ds_read_b128 token batch (group g+2,
// >=4-step slack) + per-step w-read for step+4 (exactly 4-step slack).
// 256 thr/block, 256 blocks -> 1024 waves = 1/SIMD.
// ---------------------------------------------------------------------------
__global__ __launch_bounds__(256) void rnn_kernel(const int* __restrict__ x32,
                                                  const int* __restrict__ flag,
                                                  const float* __restrict__ wtab_g,
                                                  const void* __restrict__ U_w,
                                                  const void* __restrict__ head_w,
                                                  const void* __restrict__ head_b,
                                                  float* __restrict__ out) {
    __shared__ float wtabT[16 * WSTR];  // [k][v] stride 19, folded+prescaled
    __shared__ float sU[DIM * DIM];
    __shared__ float lds_h[16][DIM];
    __shared__ int slab[2][16 * SSTR];  // token slabs, wave-private slices

    const int tid = threadIdx.x;
    const int is64 = __builtin_amdgcn_readfirstlane(flag[0]);
    const int isbf = __builtin_amdgcn_readfirstlane(flag[1]);

    // Strided fills (never the guarded-single-store bug again).
    for (int i = tid; i < 16 * WSTR; i += 256) {
        int r = i / WSTR, v = i - r * WSTR;
        float val = 0.0f;
        if (v < VOCAB) {
            float rs = 0.0f;
#pragma unroll
            for (int d = 0; d < DIM; ++d) rs += ldf(U_w, r * DIM + d, isbf);
            val = (wtab_g[v * DIM + r] + rs) * TWO_LOG2E;  // transposed+folded
        }
        wtabT[i] = val;
    }
    for (int i = tid; i < DIM * DIM; i += 256) sU[i] = ldf(U_w, i, isbf);
    __syncthreads();  // the only block-wide barrier until the head

    const int lane = tid & 63;
    const int wave = tid >> 6;
    const int g16 = lane >> 4;       // group (element) within wave
    const int k = lane & 15;         // output dim owned by this lane
    const int e = (wave << 2) | g16; // element within block
    const int gelem = (blockIdx.x << 4) | e;

    // Probe DPP ror direction (validated R12-R20).
    int p = __builtin_amdgcn_mov_dpp(k, 0x121, 0xF, 0xF, true);
    int c = (p - k) & 15;

    // ur2[j] = -2 * scale * U[k][(k + j*c) & 15], j = 0..15 (full dot).
    float ur2[16];
#pragma unroll
    for (int j = 0; j < 16; ++j)
        ur2[j] = sU[(k << 4) | ((k + j * c) & 15)] * (-2.0f * TWO_LOG2E);

    const int wb = k * WSTR;  // wtab row base (all lanes read real rows)

    // Lane's token slots in global: steps 4k..4k+3 of each 64-step blk.
    const size_t tokbase = (size_t)gelem * TLEN + (k << 2);

    int* cur = &slab[0][e * SSTR];
    int* nxt = &slab[1][e * SSTR];

    int4 g0;
#define LOADG(G, B)                                                           \
    {                                                                         \
        if (is64) {                                                           \
            const int* pp = x32 + ((tokbase + ((size_t)(B) << 6)) << 1);      \
            int4 a = *(const int4*)pp;                                        \
            int4 bq = *(const int4*)(pp + 4);                                 \
            G = make_int4(a.x, a.z, bq.x, bq.z);                              \
        } else {                                                              \
            G = *(const int4*)(x32 + tokbase + ((size_t)(B) << 6));           \
        }                                                                     \
    }

    // Prologue: slab0 <- blk0; gcur <- blk1; prime the grouped pipelines.
    LOADG(g0, 0)
    *(int4*)(cur + (k << 2)) = g0;
    int4 gcur;
    LOADG(gcur, 1)

    int4 tA = *(const int4*)(cur + 0);  // tokens, group 0 (steps 0..3)
    int4 tB = *(const int4*)(cur + 4);  // tokens, group 1
    float wq0 = wtabT[wb + tA.x];
    float wq1 = wtabT[wb + tA.y];
    float wq2 = wtabT[wb + tA.z];
    float wq3 = wtabT[wb + tA.w];

    float rst = 0.5f;  // r-state for h0 = 0

// One step: W = this step's wtab value; TN = token 4 steps ahead; WN = its
// wtab value (written; consumed next group). Core identical to R20.
#define STEP(W, TN, WN)                                                        \
    {                                                                          \
        WN = wtabT[wb + (TN)];                                                 \
        float a0 = fmaf(ur2[0], rst, W);                                       \
        float a1, a2, a3;                                                      \
        asm("s_nop 1\n\t"                                                      \
            "v_mul_f32_dpp %[a1], %[r], %[u1] row_ror:1 row_mask:0xf bank_mask:0xf\n\t"  \
            "v_mul_f32_dpp %[a2], %[r], %[u2] row_ror:2 row_mask:0xf bank_mask:0xf\n\t"  \
            "v_mul_f32_dpp %[a3], %[r], %[u3] row_ror:3 row_mask:0xf bank_mask:0xf\n\t"  \
            "v_fmac_f32_dpp %[a0], %[r], %[u4] row_ror:4 row_mask:0xf bank_mask:0xf\n\t" \
            "v_fmac_f32_dpp %[a1], %[r], %[u5] row_ror:5 row_mask:0xf bank_mask:0xf\n\t" \
            "v_fmac_f32_dpp %[a2], %[r], %[u6] row_ror:6 row_mask:0xf bank_mask:0xf\n\t" \
            "v_fmac_f32_dpp %[a3], %[r], %[u7] row_ror:7 row_mask:0xf bank_mask:0xf\n\t" \
            "v_fmac_f32_dpp %[a0], %[r], %[u8] row_ror:8 row_mask:0xf bank_mask:0xf\n\t" \
            "v_fmac_f32_dpp %[a1], %[r], %[u9] row_ror:9 row_mask:0xf bank_mask:0xf\n\t" \
            "v_fmac_f32_dpp %[a2], %[r], %[u10] row_ror:10 row_mask:0xf bank_mask:0xf\n\t" \
            "v_fmac_f32_dpp %[a3], %[r], %[u11] row_ror:11 row_mask:0xf bank_mask:0xf\n\t" \
            "v_fmac_f32_dpp %[a0], %[r], %[u12] row_ror:12 row_mask:0xf bank_mask:0xf\n\t" \
            "v_fmac_f32_dpp %[a1], %[r], %[u13] row_ror:13 row_mask:0xf bank_mask:0xf\n\t" \
            "v_fmac_f32_dpp %[a2], %[r], %[u14] row_ror:14 row_mask:0xf bank_mask:0xf\n\t" \
            "v_fmac_f32_dpp %[a3], %[r], %[u15] row_ror:15 row_mask:0xf bank_mask:0xf"     \
            : [a0] "+v"(a0), [a1] "=&v"(a1), [a2] "=&v"(a2), [a3] "=&v"(a3)    \
            : [r] "v"(rst), [u1] "v"(ur2[1]), [u2] "v"(ur2[2]),                \
              [u3] "v"(ur2[3]), [u4] "v"(ur2[4]), [u5] "v"(ur2[5]),            \
              [u6] "v"(ur2[6]), [u7] "v"(ur2[7]), [u8] "v"(ur2[8]),            \
              [u9] "v"(ur2[9]), [u10] "v"(ur2[10]), [u11] "v"(ur2[11]),        \
              [u12] "v"(ur2[12]), [u13] "v"(ur2[13]), [u14] "v"(ur2[14]),      \
              [u15] "v"(ur2[15]));                                             \
        float S = (a0 + a1) + (a2 + a3);                                       \
        rst = __builtin_amdgcn_rcpf(__builtin_amdgcn_exp2f(S) + 1.0f);         \
    }

    for (int b = 0; b < NBLK; ++b) {
        // Write next slab from gcur (loaded one blk ago), refill gcur.
        *(int4*)(nxt + (k << 2)) = gcur;
        const int nb2 = (b + 2 < NBLK) ? b + 2 : NBLK - 1;
        LOADG(gcur, nb2)

#pragma unroll
        for (int gi = 0; gi < 16; ++gi) {
            // Token batch for group gi+2 (>= 4 steps of slack).
            int4 tC = (gi < 14) ? *(const int4*)(cur + ((gi + 2) << 2))
                                : *(const int4*)(nxt + ((gi - 14) << 2));

            float wn0, wn1, wn2, wn3;
            STEP(wq0, tB.x, wn0)
            STEP(wq1, tB.y, wn1)
            STEP(wq2, tB.z, wn2)
            STEP(wq3, tB.w, wn3)

            wq0 = wn0;
            wq1 = wn1;
            wq2 = wn2;
            wq3 = wn3;
            tB = tC;
        }
        int* tmp = cur;
        cur = nxt;
        nxt = tmp;
    }

    // Head: h = 1 - 2r; out[b,v] = h . head_w[v,:] + head_b[v], f32 store.
    lds_h[e][k] = fmaf(-2.0f, rst, 1.0f);
    __syncthreads();

    for (int i = tid; i < 16 * VOCAB; i += 256) {
        int ee = i / VOCAB;
        int v = i - ee * VOCAB;
        float s = ldf(head_b, v, isbf);
#pragma unroll
        for (int d = 0; d < DIM; ++d)
            s = fmaf(lds_h[ee][d], ldf(head_w, (v << 4) + d, isbf), s);
        out[(size_t)((blockIdx.x << 4) | ee) * VOCAB + v] = s;
    }
}

extern "C" void kernel_launch(void* const* d_in, const int* in_sizes, int n_in,
                              void* d_out, int out_size, void* d_ws, size_t ws_size,
                              hipStream_t stream) {
    const int* x = (const int*)d_in[0];
    const void* emb = d_in[1];
    const void* W_w = d_in[2];
    const void* W_b = d_in[3];
    const void* U_w = d_in[4];
    const void* head_w = d_in[5];
    const void* head_b = d_in[6];

    float* wtab = (float*)d_ws;              // 288 floats
    int* flag = (int*)((char*)d_ws + 4096);  // [0]=tok is64, [1]=floats are bf16

    detect_tok<<<1, 64, 0, stream>>>(x, flag);
    detect_f<<<1, 64, 0, stream>>>((const unsigned short*)emb, flag);
    wtab_kernel<<<1, 320, 0, stream>>>(emb, W_w, W_b, flag, wtab);
    rnn_kernel<<<256, 256, 0, stream>>>(x, flag, wtab, U_w, head_w, head_b,
                                        (float*)d_out);
}